// Round 13
// baseline (243.629 us; speedup 1.0000x reference)
//
#include <hip/hip_runtime.h>
#include <hip/hip_bf16.h>

// Problem constants (match reference)
#define NN 100000      // nodes
#define NE 500000      // edges
#define DD 128         // h_dim
#define RR 230         // relation types
// F.rrelu eval-mode slope = (1/8 + 1/3)/2
#define SLOPE 0.2291666666666666667f

// Padded CSR: each node's slot count rounded up to a multiple of 8.
#define EPMAX (NE + 7 * NN)          // 1,200,000 worst-case padded slots
#define ZP (NN << 8)                 // pad slot: points at all-zero h row NN, type 0

// Fused layer kernel geometry
#define NB   192                     // nodes per block (16 waves x 12)
#define ASTR 132                     // agg_sh row stride in shorts (bank spread)

typedef __attribute__((ext_vector_type(8))) short short8;
typedef __attribute__((ext_vector_type(4))) float f32x4;

__device__ __forceinline__ short f2bf(float f) {   // RNE f32 -> bf16 bits
    unsigned u = __float_as_uint(f);
    u += 0x7fffu + ((u >> 16) & 1u);
    return (short)(u >> 16);
}
__device__ __forceinline__ unsigned pkbf(float lo, float hi) {
    return (unsigned)(unsigned short)f2bf(lo) | ((unsigned)(unsigned short)f2bf(hi) << 16);
}

// dot2: acc += x.lo*w.lo + x.hi*w.hi   (bf16 pairs packed in uint)
#if defined(__has_builtin)
#if __has_builtin(__builtin_amdgcn_fdot2_f32_bf16)
#define HAS_DOT2 1
#endif
#endif
__device__ __forceinline__ void dot2acc(float& acc, unsigned x, unsigned w) {
#ifdef HAS_DOT2
    typedef __attribute__((ext_vector_type(2))) __bf16 bf16x2;
    acc = __builtin_amdgcn_fdot2_f32_bf16(__builtin_bit_cast(bf16x2, x),
                                          __builtin_bit_cast(bf16x2, w), acc, false);
#else
    acc = fmaf(__uint_as_float(x << 16),        __uint_as_float(w << 16),
          fmaf(__uint_as_float(x & 0xFFFF0000u), __uint_as_float(w & 0xFFFF0000u), acc));
#endif
}

// ===========================================================================
// zero_k: cnt = 0
// ===========================================================================
__global__ __launch_bounds__(256) void zero_k(int* __restrict__ cnt) {
    int i = blockIdx.x * 256 + threadIdx.x;          // int4 index
    if (i * 4 < NN) *(int4*)(cnt + i * 4) = make_int4(0, 0, 0, 0);
}

// ===========================================================================
// p1_k: fused one-time prep, partitioned by blockIdx (parts independent;
// only dependency is zero_k(cnt) preceding):
//   [0,16)        : loop_weight f32 -> Wt bf16 transposed+swizzled
//   [16,74)       : relation weights -> packed bf16 pair table wb
//   [74,P1_FL_E)  : epack prefilled with ZP
//   [..,P1_HB_E)  : hb[n] = bf16(ent[node_id[n]]); row NN of hb AND hb2 = 0
//   [..,P1_TOT)   : hist: cnt[dst[e]]++
// ===========================================================================
#define P1_WT_E   16
#define P1_WB_E   74
#define P1_FL_E   (74 + (EPMAX / 4 + 255) / 256)
#define P1_HB_E   (P1_FL_E + ((NN + 1) * 16 + 255) / 256)
#define P1_TOT    (P1_HB_E + (NE + 255) / 256)

__global__ __launch_bounds__(256) void p1_k(const float* __restrict__ lw,
                                            const float* __restrict__ weight,
                                            const float* __restrict__ ent,
                                            const int* __restrict__ nid,
                                            const int* __restrict__ dst,
                                            short* __restrict__ wt,
                                            unsigned* __restrict__ wb,
                                            unsigned short* __restrict__ hb,
                                            unsigned short* __restrict__ hb2,
                                            int* __restrict__ epack,
                                            int* __restrict__ cnt) {
    int bid = blockIdx.x;
    if (bid < P1_WT_E) {
        int gid = bid * 256 + threadIdx.x;
        if (gid >= 2 * DD * 16) return;
        int l   = gid >> 11;
        int rem = gid & 2047;
        int c   = rem >> 4;
        int u   = rem & 15;
        const float* wsrc = lw + l * DD * DD + c;   // stride DD over k
        short8 v;
        #pragma unroll
        for (int j = 0; j < 8; ++j) v[j] = f2bf(wsrc[(u * 8 + j) * DD]);
        *(short8*)(wt + (size_t)l * DD * DD + c * DD + ((u ^ (c & 7)) << 3)) = v;
    } else if (bid < P1_WB_E) {
        int gid = (bid - P1_WT_E) * 256 + threadIdx.x;
        if (gid >= 2 * RR * 32) return;
        int lt = gid >> 5;           // l*RR + t
        int hl = gid & 31;
        const float* wsrc = weight + (size_t)lt * 256 + hl * 8;
        float4 f0 = *(const float4*)wsrc;
        float4 f1 = *(const float4*)(wsrc + 4);
        uint4 v;
        v.x = pkbf(f0.x, f0.z);
        v.y = pkbf(f0.y, f0.w);
        v.z = pkbf(f1.x, f1.z);
        v.w = pkbf(f1.y, f1.w);
        *(uint4*)(wb + (size_t)lt * 128 + hl * 4) = v;
    } else if (bid < P1_FL_E) {
        int idx = (bid - P1_WB_E) * 256 + threadIdx.x;   // uint4 index
        if (idx * 4 >= EPMAX) return;
        *(int4*)(epack + idx * 4) = make_int4(ZP, ZP, ZP, ZP);
    } else if (bid < P1_HB_E) {
        int gid = (bid - P1_FL_E) * 256 + threadIdx.x;
        if (gid >= (NN + 1) * 16) return;
        int n = gid >> 4;
        int u = gid & 15;
        short8 v = {0, 0, 0, 0, 0, 0, 0, 0};
        if (n < NN) {
            const float* srcp = ent + (size_t)nid[n] * DD + u * 8;
            float4 f0 = *(const float4*)srcp;
            float4 f1 = *(const float4*)(srcp + 4);
            v[0] = f2bf(f0.x); v[1] = f2bf(f0.y); v[2] = f2bf(f0.z); v[3] = f2bf(f0.w);
            v[4] = f2bf(f1.x); v[5] = f2bf(f1.y); v[6] = f2bf(f1.z); v[7] = f2bf(f1.w);
        } else {
            // zero row NN of the ping-pong buffer too (pad-slot target)
            *(short8*)(hb2 + (size_t)n * DD + u * 8) = v;
        }
        *(short8*)(hb + (size_t)n * DD + u * 8) = v;
    } else {
        int e = (bid - P1_HB_E) * 256 + threadIdx.x;
        if (e >= NE) return;
        atomicAdd(&cnt[dst[e]], 1);
    }
}

// ===========================================================================
// scan1: block-local exclusive scan of PADDED counts ((cnt+7)&~7)
// ===========================================================================
__global__ __launch_bounds__(256) void scan1_k(const int* __restrict__ cnt,
                                               int* __restrict__ off,
                                               int* __restrict__ bsum) {
    __shared__ int sh[256];
    int i = blockIdx.x * 256 + threadIdx.x;
    int v = (i < NN) ? ((cnt[i] + 7) & ~7) : 0;
    sh[threadIdx.x] = v;
    __syncthreads();
    for (int d = 1; d < 256; d <<= 1) {
        int t = (threadIdx.x >= d) ? sh[threadIdx.x - d] : 0;
        __syncthreads();
        sh[threadIdx.x] += t;
        __syncthreads();
    }
    if (i < NN) off[i] = sh[threadIdx.x] - v;
    if (threadIdx.x == 255) bsum[blockIdx.x] = sh[255];
}

// ===========================================================================
// scan23: each block re-derives its bsum prefix, adds to local offsets,
// seeds cursor; last block writes off[NN].
// ===========================================================================
__global__ __launch_bounds__(256) void scan23_k(int* __restrict__ off,
                                                const int* __restrict__ bsum,
                                                int* __restrict__ cursor,
                                                int nb) {
    __shared__ int sh[256];
    const int bid = blockIdx.x;
    const int tid = threadIdx.x;
    int s = 0;
    if (tid < bid) s = bsum[tid];
    if (tid + 256 < bid) s += bsum[tid + 256];
    sh[tid] = s;
    __syncthreads();
    #pragma unroll
    for (int d = 128; d > 0; d >>= 1) {
        if (tid < d) sh[tid] += sh[tid + d];
        __syncthreads();
    }
    const int S = sh[0];
    int i = bid * 256 + tid;
    if (i < NN) {
        int o = off[i] + S;
        off[i] = o;
        cursor[i] = o;
    }
    if (bid == nb - 1 && tid == 0) off[NN] = S + bsum[bid];
}

__global__ __launch_bounds__(256) void scat_k(const int* __restrict__ src,
                                              const int* __restrict__ et,
                                              const int* __restrict__ dst,
                                              int* __restrict__ cursor,
                                              int* __restrict__ epack) {
    int e = blockIdx.x * 256 + threadIdx.x;
    if (e >= NE) return;
    int pos = atomicAdd(&cursor[dst[e]], 1);
    epack[pos] = (src[e] << 8) | et[e];
}

// ===========================================================================
// fused_k: one RGCN layer (aggregate + self-loop MFMA + rrelu), per block.
// Block = 1024 threads (16 waves) owns NB=192 nodes; 2 blocks/CU (67 KB LDS).
//   Phase 1: wave-per-node aggregation (padded CSR, half-wave slot quads,
//            pad slots read zero h row); agg*norm -> agg_sh (LDS, bf16).
//   Phase 2: 3x 64-row MFMA sub-tiles: Ash staged (swizzled bf16), B-frags
//            read from the pre-swizzled 32 KB global wt (L1-hot), epilogue
//            rrelu(agg_sh + acc) -> hb2 (bf16) or d_out (f32).
// No aggb round-trip; layers ping-pong hb -> hb2 -> out (race-free: each
// block writes only its own output rows, reads only the layer input).
// ===========================================================================
template<int WRITE_BF16>
__global__ __launch_bounds__(1024, 2) void fused_k(
        const unsigned short* __restrict__ hsrc,
        const int* __restrict__ off,
        const int* __restrict__ epack,
        const unsigned* __restrict__ wbl,    // packed rel-weight pairs (layer)
        const short* __restrict__ wtl,       // swizzled loop-weight bf16 (layer)
        const float* __restrict__ norm,
        float* __restrict__ outf,
        unsigned short* __restrict__ outb) {
    __shared__ unsigned short agg_sh[NB * ASTR];   // 50,688 B
    __shared__ short Ash[64 * DD];                 // 16,384 B

    const int tid  = threadIdx.x;
    const int n0   = blockIdx.x * NB;
    const int lane = tid & 63;
    const int w    = tid >> 6;          // wave 0..15
    const int hl   = lane & 31;         // dim group (4 dims)
    const int h2   = lane >> 5;         // half: slot quad 4*h2..4*h2+3

    // ---------------- phase 1: aggregate (wave per node, 12 nodes/wave) ----
    {
        const char* hbb = (const char*)hsrc + hl * 8;
        const char* wbb = (const char*)wbl + hl * 16;
        #pragma unroll
        for (int i = 0; i < NB / 16; ++i) {
            int n = n0 + w + 16 * i;
            if (n >= NN) break;
            int e0 = off[n];
            int m  = off[n + 1] - e0;    // multiple of 8
            float nv = norm[n];
            float a0 = 0.f, a1 = 0.f, a2 = 0.f, a3 = 0.f;
            const int* ep = epack + e0 + h2 * 4;
            for (int j = 0; j < m; j += 8) {
                uint4 pv = *(const uint4*)(ep + j);
                uint2 x0 = *(const uint2*)(hbb + (pv.x & 0xFFFFFF00u));
                uint2 x1 = *(const uint2*)(hbb + (pv.y & 0xFFFFFF00u));
                uint2 x2 = *(const uint2*)(hbb + (pv.z & 0xFFFFFF00u));
                uint2 x3 = *(const uint2*)(hbb + (pv.w & 0xFFFFFF00u));
                uint4 w0 = *(const uint4*)(wbb + ((pv.x & 255) << 9));
                uint4 w1 = *(const uint4*)(wbb + ((pv.y & 255) << 9));
                uint4 w2 = *(const uint4*)(wbb + ((pv.z & 255) << 9));
                uint4 w3 = *(const uint4*)(wbb + ((pv.w & 255) << 9));
                dot2acc(a0, x0.x, w0.x); dot2acc(a1, x0.x, w0.y);
                dot2acc(a2, x0.y, w0.z); dot2acc(a3, x0.y, w0.w);
                dot2acc(a0, x1.x, w1.x); dot2acc(a1, x1.x, w1.y);
                dot2acc(a2, x1.y, w1.z); dot2acc(a3, x1.y, w1.w);
                dot2acc(a0, x2.x, w2.x); dot2acc(a1, x2.x, w2.y);
                dot2acc(a2, x2.y, w2.z); dot2acc(a3, x2.y, w2.w);
                dot2acc(a0, x3.x, w3.x); dot2acc(a1, x3.x, w3.y);
                dot2acc(a2, x3.y, w3.z); dot2acc(a3, x3.y, w3.w);
            }
            a0 += __shfl_xor(a0, 32);
            a1 += __shfl_xor(a1, 32);
            a2 += __shfl_xor(a2, 32);
            a3 += __shfl_xor(a3, 32);
            if (h2 == 0) {
                int nl = w + 16 * i;
                uint2 pk;
                pk.x = pkbf(a0 * nv, a1 * nv);
                pk.y = pkbf(a2 * nv, a3 * nv);
                *(uint2*)(&agg_sh[nl * ASTR + hl * 4]) = pk;
            }
        }
    }

    // ---------------- phase 2: MFMA apply, 3 sub-tiles of 64 rows ----------
    const int wm  = w >> 2;             // row group (16 rows)
    const int wn  = w & 3;              // col group (32 cols)
    const int l16 = tid & 15;
    const int q   = lane >> 4;          // 0..3
    union Frag { uint2 u2[2]; short8 s8; };

    for (int sub = 0; sub < NB / 64; ++sub) {
        __syncthreads();                // phase-1 done / prev sub-tile done
        {   // stage 64-row A tile: thread -> (row r=tid>>4, unit u=tid&15)
            int r = tid >> 4;
            int u = tid & 15;
            long srow = n0 + sub * 64 + r;
            if (srow >= NN) srow = NN - 1;     // clamp (stores guarded)
            short8 v = *(const short8*)(hsrc + (size_t)srow * DD + u * 8);
            *(short8*)(Ash + r * DD + ((u ^ (r & 7)) << 3)) = v;
        }
        __syncthreads();

        f32x4 acc[2];
        acc[0] = (f32x4){0.f, 0.f, 0.f, 0.f};
        acc[1] = (f32x4){0.f, 0.f, 0.f, 0.f};
        const int ar = wm * 16 + l16;
        const short* abase = Ash + ar * DD;
        #pragma unroll
        for (int ks = 0; ks < 4; ++ks) {
            const int ua   = ks * 4 + (q >> 1);
            const int off8 = 4 * (q & 1);
            Frag fa;
            fa.u2[0] = *(const uint2*)(abase + ((ua       ^ (ar & 7)) << 3) + off8);
            fa.u2[1] = *(const uint2*)(abase + (((ua + 2) ^ (ar & 7)) << 3) + off8);
            #pragma unroll
            for (int nt = 0; nt < 2; ++nt) {
                int c = wn * 32 + nt * 16 + l16;
                const short* bbase = wtl + (size_t)c * DD;
                Frag fb;
                fb.u2[0] = *(const uint2*)(bbase + ((ua       ^ (c & 7)) << 3) + off8);
                fb.u2[1] = *(const uint2*)(bbase + (((ua + 2) ^ (c & 7)) << 3) + off8);
                acc[nt] = __builtin_amdgcn_mfma_f32_16x16x32_bf16(fa.s8, fb.s8,
                                                                  acc[nt], 0, 0, 0);
            }
        }

        // epilogue: rrelu(agg_sh + acc) -> out
        #pragma unroll
        for (int nt = 0; nt < 2; ++nt) {
            int c = wn * 32 + nt * 16 + l16;
            #pragma unroll
            for (int i = 0; i < 4; ++i) {
                int rl = sub * 64 + wm * 16 + 4 * q + i;
                long nrow = (long)n0 + rl;
                if (nrow < NN) {
                    float g = __uint_as_float((unsigned)agg_sh[rl * ASTR + c] << 16);
                    float v = g + acc[nt][i];
                    v = (v >= 0.f) ? v : v * SLOPE;
                    if (WRITE_BF16) outb[nrow * DD + c] = (unsigned short)f2bf(v);
                    else            outf[nrow * DD + c] = v;
                }
            }
        }
    }
}

extern "C" void kernel_launch(void* const* d_in, const int* in_sizes, int n_in,
                              void* d_out, int out_size, void* d_ws, size_t ws_size,
                              hipStream_t stream) {
    const float* ent_embeds  = (const float*)d_in[0];
    // d_in[1] = rel_embeds (unused by the layer)
    const float* weight      = (const float*)d_in[2];   // [L, R, 256]
    const float* loop_weight = (const float*)d_in[3];   // [L, 128, 128]
    const float* norm        = (const float*)d_in[4];   // [N, 1]
    const int*   node_id     = (const int*)d_in[5];
    const int*   edge_type   = (const int*)d_in[6];
    const int*   src         = (const int*)d_in[7];
    const int*   dst         = (const int*)d_in[8];
    float*       out         = (float*)d_out;

    // Workspace layout (~57 MB total)
    unsigned short* hb  = (unsigned short*)d_ws;                   // (N+1)*D bf16
    unsigned short* hb2 = hb + (size_t)(NN + 1) * DD;              // (N+1)*D bf16
    int*   cnt    = (int*)(hb2 + (size_t)(NN + 1) * DD);           // NN
    int*   off    = cnt + NN;                                      // NN+1
    int*   cursor = off + NN + 1;                                  // NN
    int*   epack  = cursor + NN;                                   // EPMAX (padded)
    int*   bsum   = epack + EPMAX;                                 // 512
    short* wt     = (short*)(bsum + 512);                          // 2*DD*DD bf16
    unsigned* wb  = (unsigned*)(wt + 2 * DD * DD);                 // 2*RR*128 uints

    const int NB_E = (NE + 255) / 256;
    const int NB_N = (NN + 255) / 256;

    // ---- one-time prep: zero -> fused prep/fill/hist -> scans -> scatter ----
    zero_k  <<<(NN / 4 + 255) / 256, 256, 0, stream>>>(cnt);
    p1_k    <<<P1_TOT, 256, 0, stream>>>(loop_weight, weight, ent_embeds, node_id, dst,
                                         wt, wb, hb, hb2, epack, cnt);
    scan1_k <<<NB_N, 256, 0, stream>>>(cnt, off, bsum);
    scan23_k<<<NB_N, 256, 0, stream>>>(off, bsum, cursor, NB_N);
    scat_k  <<<NB_E, 256, 0, stream>>>(src, edge_type, dst, cursor, epack);

    const int FUSED_BLOCKS = (NN + NB - 1) / NB;   // 521

    // ---- layer 0: hb -> hb2 (bf16) ----
    fused_k<1><<<FUSED_BLOCKS, 1024, 0, stream>>>(hb, off, epack, wb, wt,
                                                  norm, nullptr, hb2);
    // ---- layer 1: hb2 -> d_out (f32) ----
    fused_k<0><<<FUSED_BLOCKS, 1024, 0, stream>>>(hb2, off, epack,
                                                  wb + (size_t)RR * 128,
                                                  wt + (size_t)DD * DD,
                                                  norm, out, nullptr);
}

// Round 14
// 207.028 us; speedup vs baseline: 1.1768x; 1.1768x over previous
//
#include <hip/hip_runtime.h>
#include <hip/hip_bf16.h>

// Problem constants (match reference)
#define NN 100000      // nodes
#define NE 500000      // edges
#define DD 128         // h_dim
#define RR 230         // relation types
// F.rrelu eval-mode slope = (1/8 + 1/3)/2
#define SLOPE 0.2291666666666666667f

// Padded CSR: each node's slot count rounded up to a multiple of 8.
#define EPMAX (NE + 7 * NN)          // 1,200,000 worst-case padded slots
#define ZP (NN << 8)                 // pad slot: points at all-zero hb row NN, type 0

typedef __attribute__((ext_vector_type(8))) short short8;
typedef __attribute__((ext_vector_type(4))) float f32x4;

__device__ __forceinline__ short f2bf(float f) {   // RNE f32 -> bf16 bits
    unsigned u = __float_as_uint(f);
    u += 0x7fffu + ((u >> 16) & 1u);
    return (short)(u >> 16);
}
__device__ __forceinline__ unsigned pkbf(float lo, float hi) {
    return (unsigned)(unsigned short)f2bf(lo) | ((unsigned)(unsigned short)f2bf(hi) << 16);
}

// dot2: acc += x.lo*w.lo + x.hi*w.hi   (bf16 pairs packed in uint)
#if defined(__has_builtin)
#if __has_builtin(__builtin_amdgcn_fdot2_f32_bf16)
#define HAS_DOT2 1
#endif
#endif
__device__ __forceinline__ void dot2acc(float& acc, unsigned x, unsigned w) {
#ifdef HAS_DOT2
    typedef __attribute__((ext_vector_type(2))) __bf16 bf16x2;
    acc = __builtin_amdgcn_fdot2_f32_bf16(__builtin_bit_cast(bf16x2, x),
                                          __builtin_bit_cast(bf16x2, w), acc, false);
#else
    acc = fmaf(__uint_as_float(x << 16),        __uint_as_float(w << 16),
          fmaf(__uint_as_float(x & 0xFFFF0000u), __uint_as_float(w & 0xFFFF0000u), acc));
#endif
}

// ===========================================================================
// zero_k: cnt = 0
// ===========================================================================
__global__ __launch_bounds__(256) void zero_k(int* __restrict__ cnt) {
    int i = blockIdx.x * 256 + threadIdx.x;          // int4 index
    if (i * 4 < NN) *(int4*)(cnt + i * 4) = make_int4(0, 0, 0, 0);
}

// ===========================================================================
// p1_k: fused one-time prep, partitioned by blockIdx (parts independent;
// only dependency is zero_k(cnt) preceding):
//   [0,16)        : loop_weight f32 -> Wt bf16 transposed+swizzled
//   [16,74)       : relation weights -> packed bf16 pair table wb
//   [74,P1_FL_E)  : epack prefilled with ZP (pad slots read zero row)
//   [..,P1_HB_E)  : hb[n] = bf16(ent[node_id[n]]); row NN = zeros
//   [..,P1_TOT)   : hist: cnt[dst[e]]++
// ===========================================================================
#define P1_WT_E   16
#define P1_WB_E   74
#define P1_FL_E   (74 + (EPMAX / 4 + 255) / 256)
#define P1_HB_E   (P1_FL_E + ((NN + 1) * 16 + 255) / 256)
#define P1_TOT    (P1_HB_E + (NE + 255) / 256)

__global__ __launch_bounds__(256) void p1_k(const float* __restrict__ lw,
                                            const float* __restrict__ weight,
                                            const float* __restrict__ ent,
                                            const int* __restrict__ nid,
                                            const int* __restrict__ dst,
                                            short* __restrict__ wt,
                                            unsigned* __restrict__ wb,
                                            unsigned short* __restrict__ hb,
                                            int* __restrict__ epack,
                                            int* __restrict__ cnt) {
    int bid = blockIdx.x;
    if (bid < P1_WT_E) {
        // ---- Wt[l][c][k] bf16, 16B-unit swizzle u^(c&7) ----
        int gid = bid * 256 + threadIdx.x;
        if (gid >= 2 * DD * 16) return;
        int l   = gid >> 11;
        int rem = gid & 2047;
        int c   = rem >> 4;
        int u   = rem & 15;
        const float* wsrc = lw + l * DD * DD + c;   // stride DD over k
        short8 v;
        #pragma unroll
        for (int j = 0; j < 8; ++j) v[j] = f2bf(wsrc[(u * 8 + j) * DD]);
        *(short8*)(wt + (size_t)l * DD * DD + c * DD + ((u ^ (c & 7)) << 3)) = v;
    } else if (bid < P1_WB_E) {
        // ---- packed bf16 pairs per (l,t,hl) ----
        int gid = (bid - P1_WT_E) * 256 + threadIdx.x;
        if (gid >= 2 * RR * 32) return;
        int lt = gid >> 5;           // l*RR + t
        int hl = gid & 31;
        const float* wsrc = weight + (size_t)lt * 256 + hl * 8;
        float4 f0 = *(const float4*)wsrc;
        float4 f1 = *(const float4*)(wsrc + 4);
        uint4 v;
        v.x = pkbf(f0.x, f0.z);
        v.y = pkbf(f0.y, f0.w);
        v.z = pkbf(f1.x, f1.z);
        v.w = pkbf(f1.y, f1.w);
        *(uint4*)(wb + (size_t)lt * 128 + hl * 4) = v;
    } else if (bid < P1_FL_E) {
        // ---- epack prefill with ZP ----
        int idx = (bid - P1_WB_E) * 256 + threadIdx.x;   // uint4 index
        if (idx * 4 >= EPMAX) return;
        *(int4*)(epack + idx * 4) = make_int4(ZP, ZP, ZP, ZP);
    } else if (bid < P1_HB_E) {
        // ---- hb[n] = bf16(ent[nid[n]]); row NN = zeros ----
        int gid = (bid - P1_FL_E) * 256 + threadIdx.x;
        if (gid >= (NN + 1) * 16) return;
        int n = gid >> 4;
        int u = gid & 15;
        short8 v = {0, 0, 0, 0, 0, 0, 0, 0};
        if (n < NN) {
            const float* srcp = ent + (size_t)nid[n] * DD + u * 8;
            float4 f0 = *(const float4*)srcp;
            float4 f1 = *(const float4*)(srcp + 4);
            v[0] = f2bf(f0.x); v[1] = f2bf(f0.y); v[2] = f2bf(f0.z); v[3] = f2bf(f0.w);
            v[4] = f2bf(f1.x); v[5] = f2bf(f1.y); v[6] = f2bf(f1.z); v[7] = f2bf(f1.w);
        }
        *(short8*)(hb + (size_t)n * DD + u * 8) = v;
    } else {
        // ---- hist: cnt[dst[e]]++ ----
        int e = (bid - P1_HB_E) * 256 + threadIdx.x;
        if (e >= NE) return;
        atomicAdd(&cnt[dst[e]], 1);
    }
}

// ===========================================================================
// scan1: block-local exclusive scan of PADDED counts ((cnt+7)&~7)
// ===========================================================================
__global__ __launch_bounds__(256) void scan1_k(const int* __restrict__ cnt,
                                               int* __restrict__ off,
                                               int* __restrict__ bsum) {
    __shared__ int sh[256];
    int i = blockIdx.x * 256 + threadIdx.x;
    int v = (i < NN) ? ((cnt[i] + 7) & ~7) : 0;
    sh[threadIdx.x] = v;
    __syncthreads();
    for (int d = 1; d < 256; d <<= 1) {
        int t = (threadIdx.x >= d) ? sh[threadIdx.x - d] : 0;
        __syncthreads();
        sh[threadIdx.x] += t;
        __syncthreads();
    }
    if (i < NN) off[i] = sh[threadIdx.x] - v;
    if (threadIdx.x == 255) bsum[blockIdx.x] = sh[255];
}

// ===========================================================================
// scan23: each block re-derives its bsum prefix, adds to local offsets,
// seeds cursor; last block writes off[NN].
// ===========================================================================
__global__ __launch_bounds__(256) void scan23_k(int* __restrict__ off,
                                                const int* __restrict__ bsum,
                                                int* __restrict__ cursor,
                                                int nb) {
    __shared__ int sh[256];
    const int bid = blockIdx.x;
    const int tid = threadIdx.x;
    int s = 0;
    if (tid < bid) s = bsum[tid];
    if (tid + 256 < bid) s += bsum[tid + 256];
    sh[tid] = s;
    __syncthreads();
    #pragma unroll
    for (int d = 128; d > 0; d >>= 1) {
        if (tid < d) sh[tid] += sh[tid + d];
        __syncthreads();
    }
    const int S = sh[0];
    int i = bid * 256 + tid;
    if (i < NN) {
        int o = off[i] + S;
        off[i] = o;
        cursor[i] = o;
    }
    if (bid == nb - 1 && tid == 0) off[NN] = S + bsum[bid];
}

__global__ __launch_bounds__(256) void scat_k(const int* __restrict__ src,
                                              const int* __restrict__ et,
                                              const int* __restrict__ dst,
                                              int* __restrict__ cursor,
                                              int* __restrict__ epack) {
    int e = blockIdx.x * 256 + threadIdx.x;
    if (e >= NE) return;
    int pos = atomicAdd(&cursor[dst[e]], 1);
    epack[pos] = (src[e] << 8) | et[e];
}

// ===========================================================================
// Aggregate: TWO nodes per wave with interleaved gather chains (2x MLP on
// the off->epack->h/w dependent chain; traffic unchanged). Padded CSR,
// branch-free inner body; group-overrun handled with WAVE-UNIFORM selects
// (ZP quad), never per-lane masks. Half h2 owns slot quad {4*h2..4*h2+3}.
// ===========================================================================
__global__ __launch_bounds__(256) void agg_k(const unsigned short* __restrict__ hb,
                                             const int* __restrict__ off,
                                             const int* __restrict__ epack,
                                             const unsigned* __restrict__ wb,  // packed pairs, this layer
                                             const float* __restrict__ norm,
                                             unsigned short* __restrict__ aggb) {
    int gw   = (blockIdx.x * 256 + threadIdx.x) >> 6;   // wave id
    int lane = threadIdx.x & 63;
    int hl   = lane & 31;        // dim group: dims 4hl..4hl+3 (blocks 2hl, 2hl+1)
    int h2   = lane >> 5;        // half: owns slot quad 4*h2..4*h2+3
    int na   = gw * 2;
    if (na >= NN) return;        // NN even -> nb always valid when na is
    int nbb  = na + 1;

    int o0 = off[na];
    int o1 = off[na + 1];        // == start of nbb
    int o2 = off[nbb + 1];
    int ma = o1 - o0;            // multiple of 8
    int mb = o2 - o1;
    int mmax = (ma > mb) ? ma : mb;

    float aa0 = 0.f, aa1 = 0.f, aa2 = 0.f, aa3 = 0.f;
    float ba0 = 0.f, ba1 = 0.f, ba2 = 0.f, ba3 = 0.f;
    const char* hbb = (const char*)hb + hl * 8;   // + dim offset within h row
    const char* wbb = (const char*)wb + hl * 16;  // + offset within packed w row
    const int*  epa = epack + o0 + h2 * 4;
    const int*  epb = epack + o1 + h2 * 4;

    for (int j = 0; j < mmax; j += 8) {
        // wave-uniform clamp: overrun groups use the ZP quad (zero-row reads)
        uint4 pva = (j < ma) ? *(const uint4*)(epa + j) : make_uint4(ZP, ZP, ZP, ZP);
        uint4 pvb = (j < mb) ? *(const uint4*)(epb + j) : make_uint4(ZP, ZP, ZP, ZP);

        uint2 xa0 = *(const uint2*)(hbb + (pva.x & 0xFFFFFF00u));
        uint2 xa1 = *(const uint2*)(hbb + (pva.y & 0xFFFFFF00u));
        uint2 xa2 = *(const uint2*)(hbb + (pva.z & 0xFFFFFF00u));
        uint2 xa3 = *(const uint2*)(hbb + (pva.w & 0xFFFFFF00u));
        uint2 xb0 = *(const uint2*)(hbb + (pvb.x & 0xFFFFFF00u));
        uint2 xb1 = *(const uint2*)(hbb + (pvb.y & 0xFFFFFF00u));
        uint2 xb2 = *(const uint2*)(hbb + (pvb.z & 0xFFFFFF00u));
        uint2 xb3 = *(const uint2*)(hbb + (pvb.w & 0xFFFFFF00u));
        uint4 wa0 = *(const uint4*)(wbb + ((pva.x & 255) << 9));
        uint4 wa1 = *(const uint4*)(wbb + ((pva.y & 255) << 9));
        uint4 wa2 = *(const uint4*)(wbb + ((pva.z & 255) << 9));
        uint4 wa3 = *(const uint4*)(wbb + ((pva.w & 255) << 9));
        uint4 wb0 = *(const uint4*)(wbb + ((pvb.x & 255) << 9));
        uint4 wb1 = *(const uint4*)(wbb + ((pvb.y & 255) << 9));
        uint4 wb2 = *(const uint4*)(wbb + ((pvb.z & 255) << 9));
        uint4 wb3 = *(const uint4*)(wbb + ((pvb.w & 255) << 9));

        dot2acc(aa0, xa0.x, wa0.x); dot2acc(aa1, xa0.x, wa0.y);
        dot2acc(aa2, xa0.y, wa0.z); dot2acc(aa3, xa0.y, wa0.w);
        dot2acc(ba0, xb0.x, wb0.x); dot2acc(ba1, xb0.x, wb0.y);
        dot2acc(ba2, xb0.y, wb0.z); dot2acc(ba3, xb0.y, wb0.w);
        dot2acc(aa0, xa1.x, wa1.x); dot2acc(aa1, xa1.x, wa1.y);
        dot2acc(aa2, xa1.y, wa1.z); dot2acc(aa3, xa1.y, wa1.w);
        dot2acc(ba0, xb1.x, wb1.x); dot2acc(ba1, xb1.x, wb1.y);
        dot2acc(ba2, xb1.y, wb1.z); dot2acc(ba3, xb1.y, wb1.w);
        dot2acc(aa0, xa2.x, wa2.x); dot2acc(aa1, xa2.x, wa2.y);
        dot2acc(aa2, xa2.y, wa2.z); dot2acc(aa3, xa2.y, wa2.w);
        dot2acc(ba0, xb2.x, wb2.x); dot2acc(ba1, xb2.x, wb2.y);
        dot2acc(ba2, xb2.y, wb2.z); dot2acc(ba3, xb2.y, wb2.w);
        dot2acc(aa0, xa3.x, wa3.x); dot2acc(aa1, xa3.x, wa3.y);
        dot2acc(aa2, xa3.y, wa3.z); dot2acc(aa3, xa3.y, wa3.w);
        dot2acc(ba0, xb3.x, wb3.x); dot2acc(ba1, xb3.x, wb3.y);
        dot2acc(ba2, xb3.y, wb3.z); dot2acc(ba3, xb3.y, wb3.w);
    }

    aa0 += __shfl_xor(aa0, 32);
    aa1 += __shfl_xor(aa1, 32);
    aa2 += __shfl_xor(aa2, 32);
    aa3 += __shfl_xor(aa3, 32);
    ba0 += __shfl_xor(ba0, 32);
    ba1 += __shfl_xor(ba1, 32);
    ba2 += __shfl_xor(ba2, 32);
    ba3 += __shfl_xor(ba3, 32);
    if (h2 == 0) {
        float nva = norm[na];
        float nvb = norm[nbb];
        uint2 pk;
        pk.x = pkbf(aa0 * nva, aa1 * nva);
        pk.y = pkbf(aa2 * nva, aa3 * nva);
        *(uint2*)(aggb + (size_t)na * DD + hl * 4) = pk;
        pk.x = pkbf(ba0 * nvb, ba1 * nvb);
        pk.y = pkbf(ba2 * nvb, ba3 * nvb);
        *(uint2*)(aggb + (size_t)nbb * DD + hl * 4) = pk;
    }
}

// ===========================================================================
// Apply: h_next[n,:] = rrelu( agg[n,:] + h[n,:] @ W )  via bf16 MFMA 16x16x32.
// A staged from the bf16 h table (pure 16B copies); W from pre-swizzled Wt.
// agg input is bf16. WRITE_BF16=1: write bf16 h_next in-place into hb
// (row-local => safe). WRITE_BF16=0: write f32 d_out.
// ===========================================================================
template<int WRITE_BF16>
__global__ __launch_bounds__(256, 2) void apply_k(const unsigned short* __restrict__ aggb,
                                                  const unsigned short* __restrict__ hb,
                                                  const short* __restrict__ Wt,
                                                  float* __restrict__ outf,
                                                  unsigned short* __restrict__ outb) {
    __shared__ short Ash[DD * DD];   // 32 KB bf16, [row][k] swizzled
    __shared__ short Wsh[DD * DD];   // 32 KB bf16, [col][k] swizzled

    const int tid = threadIdx.x;
    const long n0 = (long)blockIdx.x * 128;

    // ---- stage W: linear 32 KB copy (already swizzled in global) ----
    {
        const float4* wsrc = (const float4*)Wt;
        float4*       wdst = (float4*)Wsh;
        #pragma unroll
        for (int i = 0; i < 8; ++i) wdst[tid + i * 256] = wsrc[tid + i * 256];
    }
    // ---- stage A: row r = tid>>1, k-half hf = tid&1 (16B-unit copies) ----
    {
        const int r  = tid >> 1;
        const int hf = tid & 1;
        long srow = n0 + r;
        if (srow >= NN) srow = NN - 1;            // clamp (writes guarded)
        const unsigned short* hrow = hb + (size_t)srow * DD + hf * 64;
        short* arow = Ash + r * DD;
        #pragma unroll
        for (int uu = 0; uu < 8; ++uu) {
            int u = hf * 8 + uu;
            short8 v = *(const short8*)(hrow + uu * 8);
            *(short8*)(arow + ((u ^ (r & 7)) << 3)) = v;
        }
    }
    __syncthreads();

    const int wv  = tid >> 6;
    const int wm  = wv >> 1;          // wave row 0..1 (64 rows each)
    const int wn  = wv & 1;           // wave col 0..1 (64 cols each)
    const int l16 = tid & 15;
    const int q   = (tid & 63) >> 4;

    f32x4 acc[4][4];
    #pragma unroll
    for (int mt = 0; mt < 4; ++mt)
        #pragma unroll
        for (int nt = 0; nt < 4; ++nt) acc[mt][nt] = (f32x4){0.f, 0.f, 0.f, 0.f};

    union Frag { uint2 u2[2]; short8 s8; };

    #pragma unroll
    for (int ks = 0; ks < 4; ++ks) {
        const int ua   = ks * 4 + (q >> 1);       // unit of k = 32ks + 4q
        const int off8 = 4 * (q & 1);             // elem offset within unit
        short8 af[4], bf[4];
        #pragma unroll
        for (int mt = 0; mt < 4; ++mt) {
            int r = wm * 64 + mt * 16 + l16;
            const short* base = Ash + r * DD;
            Frag fr;
            fr.u2[0] = *(const uint2*)(base + ((ua       ^ (r & 7)) << 3) + off8);
            fr.u2[1] = *(const uint2*)(base + (((ua + 2) ^ (r & 7)) << 3) + off8);
            af[mt] = fr.s8;
        }
        #pragma unroll
        for (int nt = 0; nt < 4; ++nt) {
            int c = wn * 64 + nt * 16 + l16;
            const short* base = Wsh + c * DD;
            Frag fr;
            fr.u2[0] = *(const uint2*)(base + ((ua       ^ (c & 7)) << 3) + off8);
            fr.u2[1] = *(const uint2*)(base + (((ua + 2) ^ (c & 7)) << 3) + off8);
            bf[nt] = fr.s8;
        }
        #pragma unroll
        for (int mt = 0; mt < 4; ++mt)
            #pragma unroll
            for (int nt = 0; nt < 4; ++nt)
                acc[mt][nt] = __builtin_amdgcn_mfma_f32_16x16x32_bf16(
                                  af[mt], bf[nt], acc[mt][nt], 0, 0, 0);
    }

    // ---- epilogue: rrelu(agg + acc) ----
    #pragma unroll
    for (int mt = 0; mt < 4; ++mt) {
        #pragma unroll
        for (int i = 0; i < 4; ++i) {
            long nrow = n0 + wm * 64 + mt * 16 + 4 * q + i;
            if (nrow < NN) {
                #pragma unroll
                for (int nt = 0; nt < 4; ++nt) {
                    int c = wn * 64 + nt * 16 + l16;
                    float g = __uint_as_float((unsigned)aggb[nrow * DD + c] << 16);
                    float v = g + acc[mt][nt][i];
                    v = (v >= 0.f) ? v : v * SLOPE;
                    if (WRITE_BF16) outb[nrow * DD + c] = (unsigned short)f2bf(v);
                    else            outf[nrow * DD + c] = v;
                }
            }
        }
    }
}

extern "C" void kernel_launch(void* const* d_in, const int* in_sizes, int n_in,
                              void* d_out, int out_size, void* d_ws, size_t ws_size,
                              hipStream_t stream) {
    const float* ent_embeds  = (const float*)d_in[0];
    // d_in[1] = rel_embeds (unused by the layer)
    const float* weight      = (const float*)d_in[2];   // [L, R, 256]
    const float* loop_weight = (const float*)d_in[3];   // [L, 128, 128]
    const float* norm        = (const float*)d_in[4];   // [N, 1]
    const int*   node_id     = (const int*)d_in[5];
    const int*   edge_type   = (const int*)d_in[6];
    const int*   src         = (const int*)d_in[7];
    const int*   dst         = (const int*)d_in[8];
    float*       out         = (float*)d_out;

    // Workspace layout (~58 MB total)
    unsigned short* aggb = (unsigned short*)d_ws;                  // N*D bf16 = 25.6 MB
    unsigned short* hb   = aggb + (size_t)NN * DD;                 // (N+1)*D bf16
    int*   cnt    = (int*)(hb + (size_t)(NN + 1) * DD);            // NN
    int*   off    = cnt + NN;                                      // NN+1
    int*   cursor = off + NN + 1;                                  // NN
    int*   epack  = cursor + NN;                                   // EPMAX (padded)
    int*   bsum   = epack + EPMAX;                                 // 512
    short* wt     = (short*)(bsum + 512);                          // 2*DD*DD bf16
    unsigned* wb  = (unsigned*)(wt + 2 * DD * DD);                 // 2*RR*128 uints

    const int NB_E = (NE + 255) / 256;
    const int NB_N = (NN + 255) / 256;

    // ---- one-time prep: zero -> fused prep/fill/hist -> scans -> scatter ----
    zero_k  <<<(NN / 4 + 255) / 256, 256, 0, stream>>>(cnt);
    p1_k    <<<P1_TOT, 256, 0, stream>>>(loop_weight, weight, ent_embeds, node_id, dst,
                                         wt, wb, hb, epack, cnt);
    scan1_k <<<NB_N, 256, 0, stream>>>(cnt, off, bsum);
    scan23_k<<<NB_N, 256, 0, stream>>>(off, bsum, cursor, NB_N);
    scat_k  <<<NB_E, 256, 0, stream>>>(src, edge_type, dst, cursor, epack);

    const int AGG_BLOCKS = (NN / 2 * 64) / 256;   // two nodes per wave
    const int APL_BLOCKS = (NN + 127) / 128;      // 128 rows per block

    // ---- layer 0: agg from hb(=h0), apply writes h1 bf16 in-place into hb ----
    agg_k     <<<AGG_BLOCKS, 256, 0, stream>>>(hb, off, epack, wb, norm, aggb);
    apply_k<1><<<APL_BLOCKS, 256, 0, stream>>>(aggb, hb, wt, nullptr, hb);

    // ---- layer 1: agg from hb(=h1), apply writes final f32 out ----
    agg_k     <<<AGG_BLOCKS, 256, 0, stream>>>(hb, off, epack, wb + (size_t)RR * 128,
                                               norm, aggb);
    apply_k<0><<<APL_BLOCKS, 256, 0, stream>>>(aggb, hb, wt + (size_t)DD * DD, out, nullptr);
}

// Round 15
// 197.035 us; speedup vs baseline: 1.2365x; 1.0507x over previous
//
#include <hip/hip_runtime.h>
#include <hip/hip_bf16.h>

// Problem constants (match reference)
#define NN 100000      // nodes
#define NE 500000      // edges
#define DD 128         // h_dim
#define RR 230         // relation types
// F.rrelu eval-mode slope = (1/8 + 1/3)/2
#define SLOPE 0.2291666666666666667f

// Padded CSR: each node's slot count rounded up to a multiple of 8.
#define EPMAX (NE + 7 * NN)          // 1,200,000 worst-case padded slots
#define ZP (NN << 8)                 // pad slot: points at all-zero hb row NN, type 0

typedef __attribute__((ext_vector_type(8))) short short8;
typedef __attribute__((ext_vector_type(4))) float f32x4;

__device__ __forceinline__ short f2bf(float f) {   // RNE f32 -> bf16 bits
    unsigned u = __float_as_uint(f);
    u += 0x7fffu + ((u >> 16) & 1u);
    return (short)(u >> 16);
}
__device__ __forceinline__ unsigned pkbf(float lo, float hi) {
    return (unsigned)(unsigned short)f2bf(lo) | ((unsigned)(unsigned short)f2bf(hi) << 16);
}

// dot2: acc += x.lo*w.lo + x.hi*w.hi   (bf16 pairs packed in uint)
#if defined(__has_builtin)
#if __has_builtin(__builtin_amdgcn_fdot2_f32_bf16)
#define HAS_DOT2 1
#endif
#endif
__device__ __forceinline__ void dot2acc(float& acc, unsigned x, unsigned w) {
#ifdef HAS_DOT2
    typedef __attribute__((ext_vector_type(2))) __bf16 bf16x2;
    acc = __builtin_amdgcn_fdot2_f32_bf16(__builtin_bit_cast(bf16x2, x),
                                          __builtin_bit_cast(bf16x2, w), acc, false);
#else
    acc = fmaf(__uint_as_float(x << 16),        __uint_as_float(w << 16),
          fmaf(__uint_as_float(x & 0xFFFF0000u), __uint_as_float(w & 0xFFFF0000u), acc));
#endif
}

// ===========================================================================
// zero_k: cnt = 0
// ===========================================================================
__global__ __launch_bounds__(256) void zero_k(int* __restrict__ cnt) {
    int i = blockIdx.x * 256 + threadIdx.x;          // int4 index
    if (i * 4 < NN) *(int4*)(cnt + i * 4) = make_int4(0, 0, 0, 0);
}

// ===========================================================================
// p1_k: fused one-time prep, partitioned by blockIdx (parts independent;
// only dependency is zero_k(cnt) preceding):
//   [0,16)        : loop_weight f32 -> Wt bf16 transposed+swizzled
//   [16,74)       : relation weights -> packed bf16 pair table wb
//   [74,P1_FL_E)  : epack prefilled with ZP (pad slots read zero row)
//   [..,P1_HB_E)  : hb[n] = bf16(ent[node_id[n]]); row NN = zeros
//   [..,P1_TOT)   : hist: cnt[dst[e]]++
// ===========================================================================
#define P1_WT_E   16
#define P1_WB_E   74
#define P1_FL_E   (74 + (EPMAX / 4 + 255) / 256)
#define P1_HB_E   (P1_FL_E + ((NN + 1) * 16 + 255) / 256)
#define P1_TOT    (P1_HB_E + (NE + 255) / 256)

__global__ __launch_bounds__(256) void p1_k(const float* __restrict__ lw,
                                            const float* __restrict__ weight,
                                            const float* __restrict__ ent,
                                            const int* __restrict__ nid,
                                            const int* __restrict__ dst,
                                            short* __restrict__ wt,
                                            unsigned* __restrict__ wb,
                                            unsigned short* __restrict__ hb,
                                            int* __restrict__ epack,
                                            int* __restrict__ cnt) {
    int bid = blockIdx.x;
    if (bid < P1_WT_E) {
        // ---- Wt[l][c][k] bf16, 16B-unit swizzle u^(c&7) ----
        int gid = bid * 256 + threadIdx.x;
        if (gid >= 2 * DD * 16) return;
        int l   = gid >> 11;
        int rem = gid & 2047;
        int c   = rem >> 4;
        int u   = rem & 15;
        const float* wsrc = lw + l * DD * DD + c;   // stride DD over k
        short8 v;
        #pragma unroll
        for (int j = 0; j < 8; ++j) v[j] = f2bf(wsrc[(u * 8 + j) * DD]);
        *(short8*)(wt + (size_t)l * DD * DD + c * DD + ((u ^ (c & 7)) << 3)) = v;
    } else if (bid < P1_WB_E) {
        // ---- packed bf16 pairs per (l,t,hl) ----
        int gid = (bid - P1_WT_E) * 256 + threadIdx.x;
        if (gid >= 2 * RR * 32) return;
        int lt = gid >> 5;           // l*RR + t
        int hl = gid & 31;
        const float* wsrc = weight + (size_t)lt * 256 + hl * 8;
        float4 f0 = *(const float4*)wsrc;
        float4 f1 = *(const float4*)(wsrc + 4);
        uint4 v;
        v.x = pkbf(f0.x, f0.z);
        v.y = pkbf(f0.y, f0.w);
        v.z = pkbf(f1.x, f1.z);
        v.w = pkbf(f1.y, f1.w);
        *(uint4*)(wb + (size_t)lt * 128 + hl * 4) = v;
    } else if (bid < P1_FL_E) {
        // ---- epack prefill with ZP ----
        int idx = (bid - P1_WB_E) * 256 + threadIdx.x;   // uint4 index
        if (idx * 4 >= EPMAX) return;
        *(int4*)(epack + idx * 4) = make_int4(ZP, ZP, ZP, ZP);
    } else if (bid < P1_HB_E) {
        // ---- hb[n] = bf16(ent[nid[n]]); row NN = zeros ----
        int gid = (bid - P1_FL_E) * 256 + threadIdx.x;
        if (gid >= (NN + 1) * 16) return;
        int n = gid >> 4;
        int u = gid & 15;
        short8 v = {0, 0, 0, 0, 0, 0, 0, 0};
        if (n < NN) {
            const float* srcp = ent + (size_t)nid[n] * DD + u * 8;
            float4 f0 = *(const float4*)srcp;
            float4 f1 = *(const float4*)(srcp + 4);
            v[0] = f2bf(f0.x); v[1] = f2bf(f0.y); v[2] = f2bf(f0.z); v[3] = f2bf(f0.w);
            v[4] = f2bf(f1.x); v[5] = f2bf(f1.y); v[6] = f2bf(f1.z); v[7] = f2bf(f1.w);
        }
        *(short8*)(hb + (size_t)n * DD + u * 8) = v;
    } else {
        // ---- hist: cnt[dst[e]]++ ----
        int e = (bid - P1_HB_E) * 256 + threadIdx.x;
        if (e >= NE) return;
        atomicAdd(&cnt[dst[e]], 1);
    }
}

// ===========================================================================
// scan1: block-local exclusive scan of PADDED counts ((cnt+7)&~7)
// ===========================================================================
__global__ __launch_bounds__(256) void scan1_k(const int* __restrict__ cnt,
                                               int* __restrict__ off,
                                               int* __restrict__ bsum) {
    __shared__ int sh[256];
    int i = blockIdx.x * 256 + threadIdx.x;
    int v = (i < NN) ? ((cnt[i] + 7) & ~7) : 0;
    sh[threadIdx.x] = v;
    __syncthreads();
    for (int d = 1; d < 256; d <<= 1) {
        int t = (threadIdx.x >= d) ? sh[threadIdx.x - d] : 0;
        __syncthreads();
        sh[threadIdx.x] += t;
        __syncthreads();
    }
    if (i < NN) off[i] = sh[threadIdx.x] - v;
    if (threadIdx.x == 255) bsum[blockIdx.x] = sh[255];
}

// ===========================================================================
// scan23: each block re-derives its bsum prefix, adds to local offsets,
// seeds cursor; last block writes off[NN].
// ===========================================================================
__global__ __launch_bounds__(256) void scan23_k(int* __restrict__ off,
                                                const int* __restrict__ bsum,
                                                int* __restrict__ cursor,
                                                int nb) {
    __shared__ int sh[256];
    const int bid = blockIdx.x;
    const int tid = threadIdx.x;
    int s = 0;
    if (tid < bid) s = bsum[tid];
    if (tid + 256 < bid) s += bsum[tid + 256];
    sh[tid] = s;
    __syncthreads();
    #pragma unroll
    for (int d = 128; d > 0; d >>= 1) {
        if (tid < d) sh[tid] += sh[tid + d];
        __syncthreads();
    }
    const int S = sh[0];
    int i = bid * 256 + tid;
    if (i < NN) {
        int o = off[i] + S;
        off[i] = o;
        cursor[i] = o;
    }
    if (bid == nb - 1 && tid == 0) off[NN] = S + bsum[bid];
}

__global__ __launch_bounds__(256) void scat_k(const int* __restrict__ src,
                                              const int* __restrict__ et,
                                              const int* __restrict__ dst,
                                              int* __restrict__ cursor,
                                              int* __restrict__ epack) {
    int e = blockIdx.x * 256 + threadIdx.x;
    if (e >= NE) return;
    int pos = atomicAdd(&cursor[dst[e]], 1);
    epack[pos] = (src[e] << 8) | et[e];
}

// ===========================================================================
// Aggregate: one wave per dst node, PADDED slots, branch/mask/shfl-free.
// Half h2 owns slot quad {4*h2..4*h2+3} of each 8-slot group and reads its 4
// edge-pointers with ONE broadcast uint4 load. Pad slots hit the zero row.
// Bound by chip-wide scattered-line service of the h-row gathers (falsified
// alternatives: VALU count R10, shfl R11, weight traffic R12, fusion R13,
// chain MLP R14).
// ===========================================================================
__global__ __launch_bounds__(256) void agg_k(const unsigned short* __restrict__ hb,
                                             const int* __restrict__ off,
                                             const int* __restrict__ epack,
                                             const unsigned* __restrict__ wb,  // packed pairs, this layer
                                             const float* __restrict__ norm,
                                             unsigned short* __restrict__ aggb) {
    int n    = (blockIdx.x * 256 + threadIdx.x) >> 6;
    int lane = threadIdx.x & 63;
    int hl   = lane & 31;        // dim group: dims 4hl..4hl+3 (blocks 2hl, 2hl+1)
    int h2   = lane >> 5;        // half: owns slot quad 4*h2..4*h2+3
    if (n >= NN) return;
    int e0 = off[n];
    int m  = off[n + 1] - e0;    // multiple of 8 (padded)
    float nv = norm[n];
    float a0 = 0.f, a1 = 0.f, a2 = 0.f, a3 = 0.f;
    const char* hbb = (const char*)hb + hl * 8;   // + dim offset within h row
    const char* wbb = (const char*)wb + hl * 16;  // + offset within packed w row
    const int*  ep  = epack + e0 + h2 * 4;

    for (int j = 0; j < m; j += 8) {
        uint4 pv = *(const uint4*)(ep + j);       // broadcast 16B: 4 slot pointers
        uint2 x0 = *(const uint2*)(hbb + (pv.x & 0xFFFFFF00u));
        uint2 x1 = *(const uint2*)(hbb + (pv.y & 0xFFFFFF00u));
        uint2 x2 = *(const uint2*)(hbb + (pv.z & 0xFFFFFF00u));
        uint2 x3 = *(const uint2*)(hbb + (pv.w & 0xFFFFFF00u));
        uint4 w0 = *(const uint4*)(wbb + ((pv.x & 255) << 9));
        uint4 w1 = *(const uint4*)(wbb + ((pv.y & 255) << 9));
        uint4 w2 = *(const uint4*)(wbb + ((pv.z & 255) << 9));
        uint4 w3 = *(const uint4*)(wbb + ((pv.w & 255) << 9));
        dot2acc(a0, x0.x, w0.x); dot2acc(a1, x0.x, w0.y);
        dot2acc(a2, x0.y, w0.z); dot2acc(a3, x0.y, w0.w);
        dot2acc(a0, x1.x, w1.x); dot2acc(a1, x1.x, w1.y);
        dot2acc(a2, x1.y, w1.z); dot2acc(a3, x1.y, w1.w);
        dot2acc(a0, x2.x, w2.x); dot2acc(a1, x2.x, w2.y);
        dot2acc(a2, x2.y, w2.z); dot2acc(a3, x2.y, w2.w);
        dot2acc(a0, x3.x, w3.x); dot2acc(a1, x3.x, w3.y);
        dot2acc(a2, x3.y, w3.z); dot2acc(a3, x3.y, w3.w);
    }
    a0 += __shfl_xor(a0, 32);
    a1 += __shfl_xor(a1, 32);
    a2 += __shfl_xor(a2, 32);
    a3 += __shfl_xor(a3, 32);
    if (h2 == 0) {
        uint2 pk;
        pk.x = pkbf(a0 * nv, a1 * nv);
        pk.y = pkbf(a2 * nv, a3 * nv);
        *(uint2*)(aggb + (size_t)n * DD + hl * 4) = pk;
    }
}

// ===========================================================================
// Apply: h_next[n,:] = rrelu( agg[n,:] + h[n,:] @ W )  via bf16 MFMA 16x16x32.
// A staged from the bf16 h table (pure 16B copies); W from pre-swizzled Wt.
// agg input is bf16. WRITE_BF16=1: write bf16 h_next in-place into hb
// (row-local => safe). WRITE_BF16=0: write f32 d_out.
// ===========================================================================
template<int WRITE_BF16>
__global__ __launch_bounds__(256, 2) void apply_k(const unsigned short* __restrict__ aggb,
                                                  const unsigned short* __restrict__ hb,
                                                  const short* __restrict__ Wt,
                                                  float* __restrict__ outf,
                                                  unsigned short* __restrict__ outb) {
    __shared__ short Ash[DD * DD];   // 32 KB bf16, [row][k] swizzled
    __shared__ short Wsh[DD * DD];   // 32 KB bf16, [col][k] swizzled

    const int tid = threadIdx.x;
    const long n0 = (long)blockIdx.x * 128;

    // ---- stage W: linear 32 KB copy (already swizzled in global) ----
    {
        const float4* wsrc = (const float4*)Wt;
        float4*       wdst = (float4*)Wsh;
        #pragma unroll
        for (int i = 0; i < 8; ++i) wdst[tid + i * 256] = wsrc[tid + i * 256];
    }
    // ---- stage A: row r = tid>>1, k-half hf = tid&1 (16B-unit copies) ----
    {
        const int r  = tid >> 1;
        const int hf = tid & 1;
        long srow = n0 + r;
        if (srow >= NN) srow = NN - 1;            // clamp (writes guarded)
        const unsigned short* hrow = hb + (size_t)srow * DD + hf * 64;
        short* arow = Ash + r * DD;
        #pragma unroll
        for (int uu = 0; uu < 8; ++uu) {
            int u = hf * 8 + uu;
            short8 v = *(const short8*)(hrow + uu * 8);
            *(short8*)(arow + ((u ^ (r & 7)) << 3)) = v;
        }
    }
    __syncthreads();

    const int wv  = tid >> 6;
    const int wm  = wv >> 1;          // wave row 0..1 (64 rows each)
    const int wn  = wv & 1;           // wave col 0..1 (64 cols each)
    const int l16 = tid & 15;
    const int q   = (tid & 63) >> 4;

    f32x4 acc[4][4];
    #pragma unroll
    for (int mt = 0; mt < 4; ++mt)
        #pragma unroll
        for (int nt = 0; nt < 4; ++nt) acc[mt][nt] = (f32x4){0.f, 0.f, 0.f, 0.f};

    union Frag { uint2 u2[2]; short8 s8; };

    #pragma unroll
    for (int ks = 0; ks < 4; ++ks) {
        const int ua   = ks * 4 + (q >> 1);       // unit of k = 32ks + 4q
        const int off8 = 4 * (q & 1);             // elem offset within unit
        short8 af[4], bf[4];
        #pragma unroll
        for (int mt = 0; mt < 4; ++mt) {
            int r = wm * 64 + mt * 16 + l16;
            const short* base = Ash + r * DD;
            Frag fr;
            fr.u2[0] = *(const uint2*)(base + ((ua       ^ (r & 7)) << 3) + off8);
            fr.u2[1] = *(const uint2*)(base + (((ua + 2) ^ (r & 7)) << 3) + off8);
            af[mt] = fr.s8;
        }
        #pragma unroll
        for (int nt = 0; nt < 4; ++nt) {
            int c = wn * 64 + nt * 16 + l16;
            const short* base = Wsh + c * DD;
            Frag fr;
            fr.u2[0] = *(const uint2*)(base + ((ua       ^ (c & 7)) << 3) + off8);
            fr.u2[1] = *(const uint2*)(base + (((ua + 2) ^ (c & 7)) << 3) + off8);
            bf[nt] = fr.s8;
        }
        #pragma unroll
        for (int mt = 0; mt < 4; ++mt)
            #pragma unroll
            for (int nt = 0; nt < 4; ++nt)
                acc[mt][nt] = __builtin_amdgcn_mfma_f32_16x16x32_bf16(
                                  af[mt], bf[nt], acc[mt][nt], 0, 0, 0);
    }

    // ---- epilogue: rrelu(agg + acc) ----
    #pragma unroll
    for (int mt = 0; mt < 4; ++mt) {
        #pragma unroll
        for (int i = 0; i < 4; ++i) {
            long nrow = n0 + wm * 64 + mt * 16 + 4 * q + i;
            if (nrow < NN) {
                #pragma unroll
                for (int nt = 0; nt < 4; ++nt) {
                    int c = wn * 64 + nt * 16 + l16;
                    float g = __uint_as_float((unsigned)aggb[nrow * DD + c] << 16);
                    float v = g + acc[mt][nt][i];
                    v = (v >= 0.f) ? v : v * SLOPE;
                    if (WRITE_BF16) outb[nrow * DD + c] = (unsigned short)f2bf(v);
                    else            outf[nrow * DD + c] = v;
                }
            }
        }
    }
}

extern "C" void kernel_launch(void* const* d_in, const int* in_sizes, int n_in,
                              void* d_out, int out_size, void* d_ws, size_t ws_size,
                              hipStream_t stream) {
    const float* ent_embeds  = (const float*)d_in[0];
    // d_in[1] = rel_embeds (unused by the layer)
    const float* weight      = (const float*)d_in[2];   // [L, R, 256]
    const float* loop_weight = (const float*)d_in[3];   // [L, 128, 128]
    const float* norm        = (const float*)d_in[4];   // [N, 1]
    const int*   node_id     = (const int*)d_in[5];
    const int*   edge_type   = (const int*)d_in[6];
    const int*   src         = (const int*)d_in[7];
    const int*   dst         = (const int*)d_in[8];
    float*       out         = (float*)d_out;

    // Workspace layout (~58 MB total)
    unsigned short* aggb = (unsigned short*)d_ws;                  // N*D bf16 = 25.6 MB
    unsigned short* hb   = aggb + (size_t)NN * DD;                 // (N+1)*D bf16
    int*   cnt    = (int*)(hb + (size_t)(NN + 1) * DD);            // NN
    int*   off    = cnt + NN;                                      // NN+1
    int*   cursor = off + NN + 1;                                  // NN
    int*   epack  = cursor + NN;                                   // EPMAX (padded)
    int*   bsum   = epack + EPMAX;                                 // 512
    short* wt     = (short*)(bsum + 512);                          // 2*DD*DD bf16
    unsigned* wb  = (unsigned*)(wt + 2 * DD * DD);                 // 2*RR*128 uints

    const int NB_E = (NE + 255) / 256;
    const int NB_N = (NN + 255) / 256;

    // ---- one-time prep: zero -> fused prep/fill/hist -> scans -> scatter ----
    zero_k  <<<(NN / 4 + 255) / 256, 256, 0, stream>>>(cnt);
    p1_k    <<<P1_TOT, 256, 0, stream>>>(loop_weight, weight, ent_embeds, node_id, dst,
                                         wt, wb, hb, epack, cnt);
    scan1_k <<<NB_N, 256, 0, stream>>>(cnt, off, bsum);
    scan23_k<<<NB_N, 256, 0, stream>>>(off, bsum, cursor, NB_N);
    scat_k  <<<NB_E, 256, 0, stream>>>(src, edge_type, dst, cursor, epack);

    const int AGG_BLOCKS = (NN * 64) / 256;    // one wave per node
    const int APL_BLOCKS = (NN + 127) / 128;   // 128 rows per block

    // ---- layer 0: agg from hb(=h0), apply writes h1 bf16 in-place into hb ----
    agg_k     <<<AGG_BLOCKS, 256, 0, stream>>>(hb, off, epack, wb, norm, aggb);
    apply_k<1><<<APL_BLOCKS, 256, 0, stream>>>(aggb, hb, wt, nullptr, hb);

    // ---- layer 1: agg from hb(=h1), apply writes final f32 out ----
    agg_k     <<<AGG_BLOCKS, 256, 0, stream>>>(hb, off, epack, wb + (size_t)RR * 128,
                                               norm, aggb);
    apply_k<0><<<APL_BLOCKS, 256, 0, stream>>>(aggb, hb, wt + (size_t)DD * DD, out, nullptr);
}